// Round 3
// baseline (865.627 us; speedup 1.0000x reference)
//
#include <hip/hip_runtime.h>

#define D_FEAT 64
#define NPB 128            // nodes per bucket (dst >> 7)
#define NBMAX 1024         // padded bucket count (NB must be <= 1024)
#define CHUNK 4096         // edges per partition block
#define EPT 16             // edges per thread in partition (CHUNK/256)

// ---------------- helpers ----------------

__global__ void zero_ints(int* __restrict__ p, int n) {
    int i = blockIdx.x * blockDim.x + threadIdx.x;
    int stride = gridDim.x * blockDim.x;
    for (int j = i; j < n; j += stride) p[j] = 0;
}

// node-level degrees: hist_out[src]++, hist_in[dst]++
__global__ void histogram_kernel(const int* __restrict__ src, const int* __restrict__ dst,
                                 int n_edges, int* __restrict__ hist_out, int* __restrict__ hist_in) {
    int i = blockIdx.x * blockDim.x + threadIdx.x;
    int stride = gridDim.x * blockDim.x;
    for (int e = i; e < n_edges; e += stride) {
        atomicAdd(&hist_out[src[e]], 1);
        atomicAdd(&hist_in[dst[e]], 1);
    }
}

// oscale[i] = rsqrt(max(outdeg,1))
__global__ void oscale_kernel(const int* __restrict__ hist_out, float* __restrict__ oscale, int n) {
    int i = blockIdx.x * blockDim.x + threadIdx.x;
    if (i < n) {
        int od = hist_out[i];
        oscale[i] = rsqrtf((float)(od > 1 ? od : 1));
    }
}

// bucket counts from node in-degrees: one 64-lane wave per bucket
__global__ void bucket_cnt_kernel(const int* __restrict__ hist_in, int* __restrict__ bcnt,
                                  int n_nodes, int nb) {
    int wid = blockIdx.x * (blockDim.x >> 6) + (threadIdx.x >> 6);
    if (wid >= nb) return;
    int lane = threadIdx.x & 63;
    int base = wid * NPB;
    int i0 = base + lane, i1 = base + 64 + lane;
    int v = ((i0 < n_nodes) ? hist_in[i0] : 0) + ((i1 < n_nodes) ? hist_in[i1] : 0);
    #pragma unroll
    for (int off = 32; off > 0; off >>= 1) v += __shfl_xor(v, off);
    if (lane == 0) bcnt[wid] = v;
}

// single-block exclusive scan of bcnt[nb] -> bstart[nb+1]; gcursor = bstart
__global__ void bucket_scan_kernel(const int* __restrict__ bcnt, int* __restrict__ bstart,
                                   int* __restrict__ gcursor, int nb, int n_edges) {
    __shared__ int s[NBMAX];
    int t = threadIdx.x;
    int v = (t < nb) ? bcnt[t] : 0;
    s[t] = v;
    __syncthreads();
    for (int off = 1; off < NBMAX; off <<= 1) {
        int x = (t >= off) ? s[t - off] : 0;
        __syncthreads();
        s[t] += x;
        __syncthreads();
    }
    if (t < nb) {
        int ex = s[t] - v;
        bstart[t] = ex;
        gcursor[t] = ex;
    }
    if (t == 0) bstart[nb] = n_edges;
}

// LDS-staged partition: bucket edges by dst>>7, output packed (src<<7 | dst&127).
// Per-block local counting sort -> coalesced bucket-grouped global writes.
__global__ __launch_bounds__(256) void partition_kernel(
        const int* __restrict__ src, const int* __restrict__ dst, int n_edges,
        int* __restrict__ gcursor, int* __restrict__ sorted_pk) {
    __shared__ int lhist[NBMAX];
    __shared__ int lstart[NBMAX];
    __shared__ int ldelta[NBMAX];
    __shared__ int lcur[NBMAX];
    __shared__ int part[256];
    __shared__ int pkLDS[CHUNK];
    __shared__ unsigned short bktLDS[CHUNK];

    int t = threadIdx.x;
    long long cbase = (long long)blockIdx.x * CHUNK;
    int cnt = n_edges - cbase < CHUNK ? (int)(n_edges - cbase) : CHUNK;

    for (int i = t; i < NBMAX; i += 256) lhist[i] = 0;
    __syncthreads();

    int ssrc[EPT], sdst[EPT];
    #pragma unroll
    for (int i = 0; i < EPT; ++i) {
        long long e = cbase + t + i * 256;
        if (e < n_edges) {
            ssrc[i] = src[e];
            sdst[i] = dst[e];
            atomicAdd(&lhist[sdst[i] >> 7], 1);
        } else {
            sdst[i] = -1;
        }
    }
    __syncthreads();

    // exclusive scan of lhist[1024]: 4 entries per thread + block scan
    int b0 = 4 * t;
    int h0 = lhist[b0], h1 = lhist[b0 + 1], h2 = lhist[b0 + 2], h3 = lhist[b0 + 3];
    int tot = h0 + h1 + h2 + h3;
    part[t] = tot;
    __syncthreads();
    for (int off = 1; off < 256; off <<= 1) {
        int x = (t >= off) ? part[t - off] : 0;
        __syncthreads();
        part[t] += x;
        __syncthreads();
    }
    int ex = part[t] - tot;
    lstart[b0] = ex;
    lstart[b0 + 1] = ex + h0;
    lstart[b0 + 2] = ex + h0 + h1;
    lstart[b0 + 3] = ex + h0 + h1 + h2;
    __syncthreads();

    // claim global ranges (one atomic per nonempty bucket) + init local cursors
    for (int b = t; b < NBMAX; b += 256) {
        lcur[b] = lstart[b];
        int c = lhist[b];
        if (c > 0) {
            int g = atomicAdd(&gcursor[b], c);
            ldelta[b] = g - lstart[b];
        }
    }
    __syncthreads();

    // local scatter into bucket-grouped LDS
    #pragma unroll
    for (int i = 0; i < EPT; ++i) {
        if (sdst[i] >= 0) {
            int b = sdst[i] >> 7;
            int slot = atomicAdd(&lcur[b], 1);
            pkLDS[slot] = (ssrc[i] << 7) | (sdst[i] & 127);
            bktLDS[slot] = (unsigned short)b;
        }
    }
    __syncthreads();

    // coalesced copy out: consecutive slots of one bucket -> consecutive global
    for (int j = t; j < cnt; j += 256) {
        int b = bktLDS[j];
        sorted_pk[j + ldelta[b]] = pkLDS[j];
    }
}

// One block per bucket: 128x64 fp32 accumulator in LDS; waves broadcast edges.
__global__ __launch_bounds__(512) void aggregate_kernel(
        const float* __restrict__ emb, const int* __restrict__ sorted_pk,
        const int* __restrict__ bstart, const float* __restrict__ oscale,
        const int* __restrict__ hist_in, float* __restrict__ out, int n_nodes) {
    __shared__ float acc[NPB * D_FEAT];   // 32 KB
    int t = threadIdx.x;
    int b = blockIdx.x;
    for (int i = t; i < NPB * D_FEAT; i += 512) acc[i] = 0.f;
    __syncthreads();

    int ebeg = bstart[b], eend = bstart[b + 1];
    int wid = t >> 6, lane = t & 63;

    for (int base = ebeg + wid * 64; base < eend; base += 512) {
        int e = base + lane;
        int pk = (e < eend) ? sorted_pk[e] : 0;
        int kcnt = eend - base;
        if (kcnt > 64) kcnt = 64;
        int k = 0;
        for (; k + 4 <= kcnt; k += 4) {
            int p0 = __shfl(pk, k);
            int p1 = __shfl(pk, k + 1);
            int p2 = __shfl(pk, k + 2);
            int p3 = __shfl(pk, k + 3);
            int s0 = p0 >> 7, s1 = p1 >> 7, s2 = p2 >> 7, s3 = p3 >> 7;
            float v0 = emb[s0 * D_FEAT + lane] * oscale[s0];
            float v1 = emb[s1 * D_FEAT + lane] * oscale[s1];
            float v2 = emb[s2 * D_FEAT + lane] * oscale[s2];
            float v3 = emb[s3 * D_FEAT + lane] * oscale[s3];
            atomicAdd(&acc[(p0 & 127) * D_FEAT + lane], v0);
            atomicAdd(&acc[(p1 & 127) * D_FEAT + lane], v1);
            atomicAdd(&acc[(p2 & 127) * D_FEAT + lane], v2);
            atomicAdd(&acc[(p3 & 127) * D_FEAT + lane], v3);
        }
        for (; k < kcnt; ++k) {
            int p0 = __shfl(pk, k);
            int s0 = p0 >> 7;
            float v0 = emb[s0 * D_FEAT + lane] * oscale[s0];
            atomicAdd(&acc[(p0 & 127) * D_FEAT + lane], v0);
        }
    }
    __syncthreads();

    // scaled coalesced writeback
    int nbase = b * NPB;
    for (int i = t; i < NPB * D_FEAT; i += 512) {
        int node = nbase + (i >> 6);
        if (node < n_nodes) {
            int id = hist_in[node];
            out[(long long)node * D_FEAT + (i & 63)] = acc[i] * rsqrtf((float)(id > 1 ? id : 1));
        }
    }
}

// ---------------- fallback: atomic scatter path ----------------

__global__ void fb_zero(float* __restrict__ out, long long n_out,
                        int* __restrict__ deg, int n_deg) {
    long long i = (long long)blockIdx.x * blockDim.x + threadIdx.x;
    long long stride = (long long)gridDim.x * blockDim.x;
    for (long long j = i; j < n_out; j += stride) out[j] = 0.0f;
    for (long long j = i; j < n_deg; j += stride) deg[j] = 0;
}

__global__ void fb_scatter(const float* __restrict__ emb,
                           const int* __restrict__ src, const int* __restrict__ dst,
                           const int* __restrict__ outdeg,
                           float* __restrict__ out, int n_edges) {
    const int epb = blockDim.x >> 6;
    const int d = threadIdx.x & 63;
    long long e0 = (long long)blockIdx.x * epb + (threadIdx.x >> 6);
    long long estride = (long long)gridDim.x * epb;
    for (long long e = e0; e < n_edges; e += estride) {
        int s = src[e];
        int tt = dst[e];
        int od = outdeg[s];
        float v = emb[(long long)s * D_FEAT + d] * rsqrtf((float)(od > 1 ? od : 1));
        atomicAdd(&out[(long long)tt * D_FEAT + d], v);
    }
}

__global__ void fb_scale(float* __restrict__ out, const int* __restrict__ indeg,
                         long long n_elems) {
    long long i = (long long)blockIdx.x * blockDim.x + threadIdx.x;
    long long stride = (long long)gridDim.x * blockDim.x;
    for (long long j = i; j < n_elems; j += stride) {
        int id = indeg[(int)(j >> 6)];
        out[j] *= rsqrtf((float)(id > 1 ? id : 1));
    }
}

extern "C" void kernel_launch(void* const* d_in, const int* in_sizes, int n_in,
                              void* d_out, int out_size, void* d_ws, size_t ws_size,
                              hipStream_t stream) {
    const float* emb = (const float*)d_in[0];
    const int* src = (const int*)d_in[1];
    const int* dst = (const int*)d_in[2];
    const int n_nodes = in_sizes[0] / D_FEAT;
    const int n_edges = in_sizes[1];
    float* out = (float*)d_out;
    const int block = 256;

    const int nb = (n_nodes + NPB - 1) / NPB;   // 782 for 100K

    // workspace layout
    int* hist_out = (int*)d_ws;                      // N
    int* hist_in = hist_out + n_nodes;               // N
    float* oscale = (float*)(hist_in + n_nodes);     // N floats
    int* bcnt = (int*)(oscale + n_nodes);            // NBMAX
    int* bstart = bcnt + NBMAX;                      // NBMAX+1
    int* gcursor = bstart + NBMAX + 1;               // NBMAX
    int* sorted_pk = gcursor + NBMAX;                // E
    size_t need = ((size_t)3 * n_nodes + 3 * NBMAX + 1 + (size_t)n_edges) * sizeof(int);

    if (ws_size >= need && nb <= NBMAX && n_nodes < (1 << 17)) {
        zero_ints<<<512, block, 0, stream>>>(hist_out, 2 * n_nodes);
        histogram_kernel<<<2048, block, 0, stream>>>(src, dst, n_edges, hist_out, hist_in);
        oscale_kernel<<<(n_nodes + 255) / 256, block, 0, stream>>>(hist_out, oscale, n_nodes);
        bucket_cnt_kernel<<<(nb + 3) / 4, block, 0, stream>>>(hist_in, bcnt, n_nodes, nb);
        bucket_scan_kernel<<<1, NBMAX, 0, stream>>>(bcnt, bstart, gcursor, nb, n_edges);
        int pblocks = (n_edges + CHUNK - 1) / CHUNK;
        partition_kernel<<<pblocks, 256, 0, stream>>>(src, dst, n_edges, gcursor, sorted_pk);
        aggregate_kernel<<<nb, 512, 0, stream>>>(emb, sorted_pk, bstart, oscale,
                                                 hist_in, out, n_nodes);
    } else {
        int* outdeg = (int*)d_ws;
        int* indeg = outdeg + n_nodes;
        long long n_out = (long long)n_nodes * D_FEAT;
        fb_zero<<<2048, block, 0, stream>>>(out, n_out, outdeg, 2 * n_nodes);
        histogram_kernel<<<2048, block, 0, stream>>>(src, dst, n_edges, outdeg, indeg);
        fb_scatter<<<2048, block, 0, stream>>>(emb, src, dst, outdeg, out, n_edges);
        fb_scale<<<2048, block, 0, stream>>>(out, indeg, n_out);
    }
}

// Round 4
// 195.501 us; speedup vs baseline: 4.4277x; 4.4277x over previous
//
#include <hip/hip_runtime.h>

#define D_FEAT 64
#define NPB 128            // nodes per bucket (dst >> 7)
#define NBMAX 1024         // padded bucket count
#define CHUNK 4096         // edges per partition block
#define EPT 16             // CHUNK / 256

// ---------------- zero ----------------
__global__ void zero_ints(int* __restrict__ p, int n) {
    int i = blockIdx.x * blockDim.x + threadIdx.x;
    int stride = gridDim.x * blockDim.x;
    for (int j = i; j < n; j += stride) p[j] = 0;
}

// ---------------- src histogram + bucket counts (8 split copies) ----------------
__global__ void hist_kernel(const int* __restrict__ src, const int* __restrict__ dst,
                            int n_edges, int* __restrict__ outdeg, int* __restrict__ bcnt8) {
    __shared__ int lb[NBMAX];
    for (int i = threadIdx.x; i < NBMAX; i += blockDim.x) lb[i] = 0;
    __syncthreads();
    int i0 = blockIdx.x * blockDim.x + threadIdx.x;
    int stride = gridDim.x * blockDim.x;
    for (int e = i0; e < n_edges; e += stride) {
        atomicAdd(&outdeg[src[e]], 1);          // fire-and-forget int atomic
        atomicAdd(&lb[dst[e] >> 7], 1);         // LDS bucket hist
    }
    __syncthreads();
    int* my = bcnt8 + (blockIdx.x & 7) * NBMAX; // split copies kill line contention
    for (int i = threadIdx.x; i < NBMAX; i += blockDim.x)
        if (lb[i]) atomicAdd(&my[i], lb[i]);
}

__global__ void oscale_kernel(const int* __restrict__ outdeg, float* __restrict__ oscale, int n) {
    int i = blockIdx.x * blockDim.x + threadIdx.x;
    if (i < n) {
        int od = outdeg[i];
        oscale[i] = rsqrtf((float)(od > 1 ? od : 1));
    }
}

// single block, 1024 threads: sum 8 copies, exclusive scan -> bstart, gcursor
__global__ void bucket_scan_kernel(const int* __restrict__ bcnt8, int* __restrict__ bstart,
                                   int* __restrict__ gcursor) {
    __shared__ int s[NBMAX];
    int t = threadIdx.x;
    int v = 0;
    #pragma unroll
    for (int c = 0; c < 8; ++c) v += bcnt8[c * NBMAX + t];
    s[t] = v;
    __syncthreads();
    for (int off = 1; off < NBMAX; off <<= 1) {
        int x = (t >= off) ? s[t - off] : 0;
        __syncthreads();
        s[t] += x;
        __syncthreads();
    }
    int ex = s[t] - v;
    bstart[t] = ex;
    gcursor[t] = ex;
    if (t == NBMAX - 1) bstart[NBMAX] = ex + v;
}

// ---------------- partition: bucket by dst>>7, pk = (src<<7)|(dst&127) ----------------
__global__ __launch_bounds__(256) void partition_kernel(
        const int* __restrict__ src, const int* __restrict__ dst, int n_edges,
        int* __restrict__ gcursor, int* __restrict__ arrA) {
    __shared__ int lhist[NBMAX];
    __shared__ int lstart[NBMAX];
    __shared__ int ldelta[NBMAX];
    __shared__ int lcur[NBMAX];
    __shared__ int part[256];
    __shared__ int pkLDS[CHUNK];
    __shared__ unsigned short bktLDS[CHUNK];

    int t = threadIdx.x;
    long long cbase = (long long)blockIdx.x * CHUNK;
    int cnt = n_edges - cbase < CHUNK ? (int)(n_edges - cbase) : CHUNK;

    for (int i = t; i < NBMAX; i += 256) lhist[i] = 0;
    __syncthreads();

    int ssrc[EPT], sdst[EPT];
    #pragma unroll
    for (int i = 0; i < EPT; ++i) {
        long long e = cbase + t + i * 256;
        if (e < n_edges) {
            ssrc[i] = src[e];
            sdst[i] = dst[e];
            atomicAdd(&lhist[sdst[i] >> 7], 1);
        } else {
            sdst[i] = -1;
        }
    }
    __syncthreads();

    int b0 = 4 * t;
    int h0 = lhist[b0], h1 = lhist[b0 + 1], h2 = lhist[b0 + 2], h3 = lhist[b0 + 3];
    int tot = h0 + h1 + h2 + h3;
    part[t] = tot;
    __syncthreads();
    for (int off = 1; off < 256; off <<= 1) {
        int x = (t >= off) ? part[t - off] : 0;
        __syncthreads();
        part[t] += x;
        __syncthreads();
    }
    int ex = part[t] - tot;
    lstart[b0] = ex;
    lstart[b0 + 1] = ex + h0;
    lstart[b0 + 2] = ex + h0 + h1;
    lstart[b0 + 3] = ex + h0 + h1 + h2;
    __syncthreads();

    for (int b = t; b < NBMAX; b += 256) {
        lcur[b] = lstart[b];
        int c = lhist[b];
        if (c > 0) {
            int g = atomicAdd(&gcursor[b], c);
            ldelta[b] = g - lstart[b];
        }
    }
    __syncthreads();

    #pragma unroll
    for (int i = 0; i < EPT; ++i) {
        if (sdst[i] >= 0) {
            int b = sdst[i] >> 7;
            int slot = atomicAdd(&lcur[b], 1);
            pkLDS[slot] = (ssrc[i] << 7) | (sdst[i] & 127);
            bktLDS[slot] = (unsigned short)b;
        }
    }
    __syncthreads();

    for (int j = t; j < cnt; j += 256) {
        int b = bktLDS[j];
        arrA[j + ldelta[b]] = pkLDS[j];
    }
}

// ---------------- per-bucket counting sort -> CSR (starts, iscale, sorted src) ----------
__global__ __launch_bounds__(256) void bucket_sort_kernel(
        const int* __restrict__ arrA, const int* __restrict__ bstart,
        int* __restrict__ arrB, int* __restrict__ starts,
        float* __restrict__ iscale, int n_nodes, int n_edges) {
    __shared__ int lh[NPB];
    __shared__ int lst[NPB];
    __shared__ int lcur[NPB];
    int b = blockIdx.x, t = threadIdx.x;
    int s = bstart[b], e = bstart[b + 1];
    int cnt = e - s;
    for (int i = t; i < NPB; i += 256) lh[i] = 0;
    __syncthreads();
    for (int i = t; i < cnt; i += 256) atomicAdd(&lh[arrA[s + i] & 127], 1);
    __syncthreads();
    if (t < 64) {
        int l0 = lh[t], l1 = lh[t + 64];
        int a = l0;
        for (int off = 1; off < 64; off <<= 1) { int y = __shfl_up(a, off); if (t >= off) a += y; }
        int tot0 = __shfl(a, 63);
        int c = l1;
        for (int off = 1; off < 64; off <<= 1) { int y = __shfl_up(c, off); if (t >= off) c += y; }
        lst[t] = a - l0;
        lst[t + 64] = tot0 + c - l1;
    }
    __syncthreads();
    int nbase = b * NPB;
    for (int i = t; i < NPB; i += 256) {
        lcur[i] = lst[i];
        int node = nbase + i;
        if (node < n_nodes) {
            starts[node] = s + lst[i];
            int id = lh[i];
            iscale[node] = rsqrtf((float)(id > 1 ? id : 1));
        }
    }
    if (b == 0 && t == 0) starts[n_nodes] = n_edges;
    __syncthreads();
    for (int i = t; i < cnt; i += 256) {
        int v = arrA[s + i];
        int slot = s + atomicAdd(&lcur[v & 127], 1);
        arrB[slot] = v >> 7;   // sorted src; scatter stays within 8KB L2 window
    }
}

// ---------------- CSR aggregate: one wave per node, register accumulation ----------
__global__ __launch_bounds__(256) void aggregate_kernel(
        const float* __restrict__ emb, const int* __restrict__ arrB,
        const int* __restrict__ starts, const float* __restrict__ oscale,
        const float* __restrict__ iscale, float* __restrict__ out, int n_nodes) {
    int node = blockIdx.x * 4 + (threadIdx.x >> 6);
    if (node >= n_nodes) return;
    int d = threadIdx.x & 63;
    int e = starts[node];
    int e1 = starts[node + 1];
    float a0 = 0.f, a1 = 0.f, a2 = 0.f, a3 = 0.f;
    for (; e + 4 <= e1; e += 4) {
        int i0 = arrB[e], i1 = arrB[e + 1], i2 = arrB[e + 2], i3 = arrB[e + 3];
        a0 += emb[i0 * D_FEAT + d] * oscale[i0];
        a1 += emb[i1 * D_FEAT + d] * oscale[i1];
        a2 += emb[i2 * D_FEAT + d] * oscale[i2];
        a3 += emb[i3 * D_FEAT + d] * oscale[i3];
    }
    for (; e < e1; ++e) {
        int i0 = arrB[e];
        a0 += emb[i0 * D_FEAT + d] * oscale[i0];
    }
    out[(long long)node * D_FEAT + d] = ((a0 + a1) + (a2 + a3)) * iscale[node];
}

// ---------------- fallback: atomic scatter path ----------------
__global__ void fb_zero(float* __restrict__ out, long long n_out,
                        int* __restrict__ deg, int n_deg) {
    long long i = (long long)blockIdx.x * blockDim.x + threadIdx.x;
    long long stride = (long long)gridDim.x * blockDim.x;
    for (long long j = i; j < n_out; j += stride) out[j] = 0.0f;
    for (long long j = i; j < n_deg; j += stride) deg[j] = 0;
}

__global__ void fb_degree(const int* __restrict__ src, const int* __restrict__ dst,
                          int n_edges, int* __restrict__ outdeg, int* __restrict__ indeg) {
    int i = blockIdx.x * blockDim.x + threadIdx.x;
    int stride = gridDim.x * blockDim.x;
    for (int e = i; e < n_edges; e += stride) {
        atomicAdd(&outdeg[src[e]], 1);
        atomicAdd(&indeg[dst[e]], 1);
    }
}

__global__ void fb_scatter(const float* __restrict__ emb,
                           const int* __restrict__ src, const int* __restrict__ dst,
                           const int* __restrict__ outdeg,
                           float* __restrict__ out, int n_edges) {
    const int epb = blockDim.x >> 6;
    const int d = threadIdx.x & 63;
    long long e0 = (long long)blockIdx.x * epb + (threadIdx.x >> 6);
    long long estride = (long long)gridDim.x * epb;
    for (long long e = e0; e < n_edges; e += estride) {
        int s = src[e];
        int tt = dst[e];
        int od = outdeg[s];
        float v = emb[(long long)s * D_FEAT + d] * rsqrtf((float)(od > 1 ? od : 1));
        atomicAdd(&out[(long long)tt * D_FEAT + d], v);
    }
}

__global__ void fb_scale(float* __restrict__ out, const int* __restrict__ indeg,
                         long long n_elems) {
    long long i = (long long)blockIdx.x * blockDim.x + threadIdx.x;
    long long stride = (long long)gridDim.x * blockDim.x;
    for (long long j = i; j < n_elems; j += stride) {
        int id = indeg[(int)(j >> 6)];
        out[j] *= rsqrtf((float)(id > 1 ? id : 1));
    }
}

extern "C" void kernel_launch(void* const* d_in, const int* in_sizes, int n_in,
                              void* d_out, int out_size, void* d_ws, size_t ws_size,
                              hipStream_t stream) {
    const float* emb = (const float*)d_in[0];
    const int* src = (const int*)d_in[1];
    const int* dst = (const int*)d_in[2];
    const int n_nodes = in_sizes[0] / D_FEAT;
    const int n_edges = in_sizes[1];
    float* out = (float*)d_out;
    const int block = 256;
    const int nb = (n_nodes + NPB - 1) / NPB;

    // workspace layout (ints)
    int* outdeg = (int*)d_ws;                        // N
    float* oscale = (float*)(outdeg + n_nodes);      // N
    float* iscale = oscale + n_nodes;                // N
    int* bcnt8 = (int*)(iscale + n_nodes);           // 8*NBMAX
    int* bstart = bcnt8 + 8 * NBMAX;                 // NBMAX+1
    int* gcursor = bstart + NBMAX + 1;               // NBMAX
    int* starts = gcursor + NBMAX;                   // N+1
    int* arrA = starts + n_nodes + 1;                // E
    int* arrB = arrA + n_edges;                      // E
    size_t need = ((size_t)4 * n_nodes + 9 * NBMAX + 2 + 2 * (size_t)n_edges) * sizeof(int);

    if (ws_size >= need && nb <= NBMAX) {
        zero_ints<<<512, block, 0, stream>>>(outdeg, n_nodes);
        zero_ints<<<64, block, 0, stream>>>(bcnt8, 8 * NBMAX);
        hist_kernel<<<256, block, 0, stream>>>(src, dst, n_edges, outdeg, bcnt8);
        oscale_kernel<<<(n_nodes + 255) / 256, block, 0, stream>>>(outdeg, oscale, n_nodes);
        bucket_scan_kernel<<<1, NBMAX, 0, stream>>>(bcnt8, bstart, gcursor);
        int pblocks = (n_edges + CHUNK - 1) / CHUNK;
        partition_kernel<<<pblocks, 256, 0, stream>>>(src, dst, n_edges, gcursor, arrA);
        bucket_sort_kernel<<<nb, 256, 0, stream>>>(arrA, bstart, arrB, starts,
                                                   iscale, n_nodes, n_edges);
        aggregate_kernel<<<(n_nodes + 3) / 4, block, 0, stream>>>(emb, arrB, starts,
                                                                  oscale, iscale, out, n_nodes);
    } else {
        int* foutdeg = (int*)d_ws;
        int* findeg = foutdeg + n_nodes;
        long long n_out = (long long)n_nodes * D_FEAT;
        fb_zero<<<2048, block, 0, stream>>>(out, n_out, foutdeg, 2 * n_nodes);
        fb_degree<<<2048, block, 0, stream>>>(src, dst, n_edges, foutdeg, findeg);
        fb_scatter<<<2048, block, 0, stream>>>(emb, src, dst, foutdeg, out, n_edges);
        fb_scale<<<2048, block, 0, stream>>>(out, findeg, n_out);
    }
}

// Round 5
// 175.787 us; speedup vs baseline: 4.9243x; 1.1121x over previous
//
#include <hip/hip_runtime.h>

#define D_FEAT 64
#define NPB 128            // nodes per bucket (node >> 7)
#define NBMAX 1024         // padded bucket count (pow2 for scan)
#define CHUNK 4096         // edges per partition block
#define EPT 16             // CHUNK / 256

// ---------------- zero ----------------
__global__ void zero_ints(int* __restrict__ p, int n) {
    int i = blockIdx.x * blockDim.x + threadIdx.x;
    int stride = gridDim.x * blockDim.x;
    for (int j = i; j < n; j += stride) p[j] = 0;
}

// ---------------- bucket counts for BOTH sides (LDS hist, split-copy flush) -------
__global__ __launch_bounds__(256) void bcnt_kernel(
        const int* __restrict__ src, const int* __restrict__ dst, int n_edges,
        int* __restrict__ dbcnt8, int* __restrict__ sbcnt8) {
    __shared__ int ld[NBMAX];
    __shared__ int ls[NBMAX];
    int t = threadIdx.x;
    for (int i = t; i < NBMAX; i += 256) { ld[i] = 0; ls[i] = 0; }
    __syncthreads();
    int i0 = blockIdx.x * blockDim.x + t;
    int stride = gridDim.x * blockDim.x;
    for (int e = i0; e < n_edges; e += stride) {
        atomicAdd(&ld[dst[e] >> 7], 1);
        atomicAdd(&ls[src[e] >> 7], 1);
    }
    __syncthreads();
    int* dmy = dbcnt8 + (blockIdx.x & 7) * NBMAX;
    int* smy = sbcnt8 + (blockIdx.x & 7) * NBMAX;
    for (int i = t; i < NBMAX; i += 256) {
        if (ld[i]) atomicAdd(&dmy[i], ld[i]);
        if (ls[i]) atomicAdd(&smy[i], ls[i]);
    }
}

// ---------------- dual exclusive scan (one block, 1024 threads) ----------------
__global__ void scan2_kernel(const int* __restrict__ dbcnt8, const int* __restrict__ sbcnt8,
                             int* __restrict__ dbstart, int* __restrict__ gcursor,
                             int* __restrict__ sbstart, int* __restrict__ scursor) {
    __shared__ int s[NBMAX];
    int t = threadIdx.x;
    int v = 0;
    #pragma unroll
    for (int c = 0; c < 8; ++c) v += dbcnt8[c * NBMAX + t];
    s[t] = v;
    __syncthreads();
    for (int off = 1; off < NBMAX; off <<= 1) {
        int x = (t >= off) ? s[t - off] : 0;
        __syncthreads();
        s[t] += x;
        __syncthreads();
    }
    int ex = s[t] - v;
    dbstart[t] = ex;
    gcursor[t] = ex;
    if (t == NBMAX - 1) dbstart[NBMAX] = ex + v;
    __syncthreads();
    int v2 = 0;
    #pragma unroll
    for (int c = 0; c < 8; ++c) v2 += sbcnt8[c * NBMAX + t];
    s[t] = v2;
    __syncthreads();
    for (int off = 1; off < NBMAX; off <<= 1) {
        int x = (t >= off) ? s[t - off] : 0;
        __syncthreads();
        s[t] += x;
        __syncthreads();
    }
    int ex2 = s[t] - v2;
    sbstart[t] = ex2;
    scursor[t] = ex2;
    if (t == NBMAX - 1) sbstart[NBMAX] = ex2 + v2;
}

// ---------------- dst partition: pk = (src<<7)|(dst&127), bucket dst>>7 ----------
__global__ __launch_bounds__(256) void partition_kernel(
        const int* __restrict__ src, const int* __restrict__ dst, int n_edges,
        int* __restrict__ gcursor, int* __restrict__ arrA) {
    __shared__ int lhist[NBMAX];
    __shared__ int lstart[NBMAX];
    __shared__ int ldelta[NBMAX];
    __shared__ int lcur[NBMAX];
    __shared__ int part[256];
    __shared__ int pkLDS[CHUNK];
    __shared__ unsigned short bktLDS[CHUNK];

    int t = threadIdx.x;
    long long cbase = (long long)blockIdx.x * CHUNK;
    int cnt = n_edges - cbase < CHUNK ? (int)(n_edges - cbase) : CHUNK;

    for (int i = t; i < NBMAX; i += 256) lhist[i] = 0;
    __syncthreads();

    int ssrc[EPT], sdst[EPT];
    #pragma unroll
    for (int i = 0; i < EPT; ++i) {
        long long e = cbase + t + i * 256;
        if (e < n_edges) {
            ssrc[i] = src[e];
            sdst[i] = dst[e];
            atomicAdd(&lhist[sdst[i] >> 7], 1);
        } else {
            sdst[i] = -1;
        }
    }
    __syncthreads();

    int b0 = 4 * t;
    int h0 = lhist[b0], h1 = lhist[b0 + 1], h2 = lhist[b0 + 2], h3 = lhist[b0 + 3];
    int tot = h0 + h1 + h2 + h3;
    part[t] = tot;
    __syncthreads();
    for (int off = 1; off < 256; off <<= 1) {
        int x = (t >= off) ? part[t - off] : 0;
        __syncthreads();
        part[t] += x;
        __syncthreads();
    }
    int ex = part[t] - tot;
    lstart[b0] = ex;
    lstart[b0 + 1] = ex + h0;
    lstart[b0 + 2] = ex + h0 + h1;
    lstart[b0 + 3] = ex + h0 + h1 + h2;
    __syncthreads();

    for (int b = t; b < NBMAX; b += 256) {
        lcur[b] = lstart[b];
        int c = lhist[b];
        if (c > 0) {
            int g = atomicAdd(&gcursor[b], c);
            ldelta[b] = g - lstart[b];
        }
    }
    __syncthreads();

    #pragma unroll
    for (int i = 0; i < EPT; ++i) {
        if (sdst[i] >= 0) {
            int b = sdst[i] >> 7;
            int slot = atomicAdd(&lcur[b], 1);
            pkLDS[slot] = (ssrc[i] << 7) | (sdst[i] & 127);
            bktLDS[slot] = (unsigned short)b;
        }
    }
    __syncthreads();

    for (int j = t; j < cnt; j += 256) {
        int b = bktLDS[j];
        arrA[j + ldelta[b]] = pkLDS[j];
    }
}

// ---------------- src partition: bytes (src&127), bucket src>>7 ----------------
__global__ __launch_bounds__(256) void spartition_kernel(
        const int* __restrict__ src, int n_edges,
        int* __restrict__ scursor, unsigned char* __restrict__ arrS) {
    __shared__ int lhist[NBMAX];
    __shared__ int lstart[NBMAX];
    __shared__ int ldelta[NBMAX];
    __shared__ int lcur[NBMAX];
    __shared__ int part[256];
    __shared__ unsigned char stg[CHUNK];
    __shared__ unsigned short bktLDS[CHUNK];

    int t = threadIdx.x;
    long long cbase = (long long)blockIdx.x * CHUNK;
    int cnt = n_edges - cbase < CHUNK ? (int)(n_edges - cbase) : CHUNK;

    for (int i = t; i < NBMAX; i += 256) lhist[i] = 0;
    __syncthreads();

    int ssrc[EPT];
    #pragma unroll
    for (int i = 0; i < EPT; ++i) {
        long long e = cbase + t + i * 256;
        if (e < n_edges) {
            ssrc[i] = src[e];
            atomicAdd(&lhist[ssrc[i] >> 7], 1);
        } else {
            ssrc[i] = -1;
        }
    }
    __syncthreads();

    int b0 = 4 * t;
    int h0 = lhist[b0], h1 = lhist[b0 + 1], h2 = lhist[b0 + 2], h3 = lhist[b0 + 3];
    int tot = h0 + h1 + h2 + h3;
    part[t] = tot;
    __syncthreads();
    for (int off = 1; off < 256; off <<= 1) {
        int x = (t >= off) ? part[t - off] : 0;
        __syncthreads();
        part[t] += x;
        __syncthreads();
    }
    int ex = part[t] - tot;
    lstart[b0] = ex;
    lstart[b0 + 1] = ex + h0;
    lstart[b0 + 2] = ex + h0 + h1;
    lstart[b0 + 3] = ex + h0 + h1 + h2;
    __syncthreads();

    for (int b = t; b < NBMAX; b += 256) {
        lcur[b] = lstart[b];
        int c = lhist[b];
        if (c > 0) {
            int g = atomicAdd(&scursor[b], c);
            ldelta[b] = g - lstart[b];
        }
    }
    __syncthreads();

    #pragma unroll
    for (int i = 0; i < EPT; ++i) {
        if (ssrc[i] >= 0) {
            int b = ssrc[i] >> 7;
            int slot = atomicAdd(&lcur[b], 1);
            stg[slot] = (unsigned char)(ssrc[i] & 127);
            bktLDS[slot] = (unsigned short)b;
        }
    }
    __syncthreads();

    for (int j = t; j < cnt; j += 256) {
        int b = bktLDS[j];
        arrS[j + ldelta[b]] = stg[j];
    }
}

// ---------------- per-bucket out-degree -> oscale (no global atomics) -----------
__global__ __launch_bounds__(256) void src_count_kernel(
        const unsigned char* __restrict__ arrS, const int* __restrict__ sbstart,
        float* __restrict__ oscale, int n_nodes) {
    __shared__ int lh[NPB];
    int b = blockIdx.x, t = threadIdx.x;
    int s = sbstart[b], e = sbstart[b + 1];
    if (t < NPB) lh[t] = 0;
    __syncthreads();
    for (int i = s + t; i < e; i += 256) atomicAdd(&lh[arrS[i]], 1);
    __syncthreads();
    if (t < NPB) {
        int node = b * NPB + t;
        if (node < n_nodes) {
            int od = lh[t];
            oscale[node] = rsqrtf((float)(od > 1 ? od : 1));
        }
    }
}

// ---------------- per-bucket counting sort -> CSR ----------------
__global__ __launch_bounds__(256) void bucket_sort_kernel(
        const int* __restrict__ arrA, const int* __restrict__ bstart,
        int* __restrict__ arrB, int* __restrict__ starts,
        float* __restrict__ iscale, int n_nodes, int n_edges) {
    __shared__ int lh[NPB];
    __shared__ int lst[NPB];
    __shared__ int lcur[NPB];
    int b = blockIdx.x, t = threadIdx.x;
    int s = bstart[b], e = bstart[b + 1];
    int cnt = e - s;
    for (int i = t; i < NPB; i += 256) lh[i] = 0;
    __syncthreads();
    for (int i = t; i < cnt; i += 256) atomicAdd(&lh[arrA[s + i] & 127], 1);
    __syncthreads();
    if (t < 64) {
        int l0 = lh[t], l1 = lh[t + 64];
        int a = l0;
        for (int off = 1; off < 64; off <<= 1) { int y = __shfl_up(a, off); if (t >= off) a += y; }
        int tot0 = __shfl(a, 63);
        int c = l1;
        for (int off = 1; off < 64; off <<= 1) { int y = __shfl_up(c, off); if (t >= off) c += y; }
        lst[t] = a - l0;
        lst[t + 64] = tot0 + c - l1;
    }
    __syncthreads();
    int nbase = b * NPB;
    for (int i = t; i < NPB; i += 256) {
        lcur[i] = lst[i];
        int node = nbase + i;
        if (node < n_nodes) {
            starts[node] = s + lst[i];
            int id = lh[i];
            iscale[node] = rsqrtf((float)(id > 1 ? id : 1));
        }
    }
    if (b == 0 && t == 0) starts[n_nodes] = n_edges;
    __syncthreads();
    for (int i = t; i < cnt; i += 256) {
        int v = arrA[s + i];
        int slot = s + atomicAdd(&lcur[v & 127], 1);
        arrB[slot] = v >> 7;
    }
}

// ---------------- aggregate: 1 wave/node, 4 groups x 16 lanes, float4 rows -------
__global__ __launch_bounds__(256) void aggregate_kernel(
        const float* __restrict__ emb, const int* __restrict__ arrB,
        const int* __restrict__ starts, const float* __restrict__ oscale,
        const float* __restrict__ iscale, float* __restrict__ out, int n_nodes) {
    int node = blockIdx.x * 4 + (threadIdx.x >> 6);
    if (node >= n_nodes) return;
    int L = threadIdx.x & 63;
    int g = L >> 4;        // edge group 0..3
    int c = L & 15;        // float4 chunk within row
    int e0 = starts[node];
    int e1 = starts[node + 1];
    const float4* emb4 = (const float4*)emb;
    float ax = 0.f, ay = 0.f, az = 0.f, aw = 0.f;
    for (int e = e0; e < e1; e += 8) {
        int ea = e + g, eb = e + 4 + g;
        bool oka = ea < e1, okb = eb < e1;
        int sa = oka ? arrB[ea] : 0;
        int sb = okb ? arrB[eb] : 0;
        float fa = oka ? oscale[sa] : 0.f;
        float fb = okb ? oscale[sb] : 0.f;
        float4 va = emb4[sa * 16 + c];
        float4 vb = emb4[sb * 16 + c];
        ax += va.x * fa; ay += va.y * fa; az += va.z * fa; aw += va.w * fa;
        ax += vb.x * fb; ay += vb.y * fb; az += vb.z * fb; aw += vb.w * fb;
    }
    // reduce across the 4 edge-groups (lanes differing in bits 4,5)
    ax += __shfl_xor(ax, 16); ay += __shfl_xor(ay, 16);
    az += __shfl_xor(az, 16); aw += __shfl_xor(aw, 16);
    ax += __shfl_xor(ax, 32); ay += __shfl_xor(ay, 32);
    az += __shfl_xor(az, 32); aw += __shfl_xor(aw, 32);
    if (g == 0) {
        float is = iscale[node];
        float4 r;
        r.x = ax * is; r.y = ay * is; r.z = az * is; r.w = aw * is;
        ((float4*)out)[node * 16 + c] = r;
    }
}

// ---------------- fallback: atomic scatter path ----------------
__global__ void fb_zero(float* __restrict__ out, long long n_out,
                        int* __restrict__ deg, int n_deg) {
    long long i = (long long)blockIdx.x * blockDim.x + threadIdx.x;
    long long stride = (long long)gridDim.x * blockDim.x;
    for (long long j = i; j < n_out; j += stride) out[j] = 0.0f;
    for (long long j = i; j < n_deg; j += stride) deg[j] = 0;
}

__global__ void fb_degree(const int* __restrict__ src, const int* __restrict__ dst,
                          int n_edges, int* __restrict__ outdeg, int* __restrict__ indeg) {
    int i = blockIdx.x * blockDim.x + threadIdx.x;
    int stride = gridDim.x * blockDim.x;
    for (int e = i; e < n_edges; e += stride) {
        atomicAdd(&outdeg[src[e]], 1);
        atomicAdd(&indeg[dst[e]], 1);
    }
}

__global__ void fb_scatter(const float* __restrict__ emb,
                           const int* __restrict__ src, const int* __restrict__ dst,
                           const int* __restrict__ outdeg,
                           float* __restrict__ out, int n_edges) {
    const int epb = blockDim.x >> 6;
    const int d = threadIdx.x & 63;
    long long e0 = (long long)blockIdx.x * epb + (threadIdx.x >> 6);
    long long estride = (long long)gridDim.x * epb;
    for (long long e = e0; e < n_edges; e += estride) {
        int s = src[e];
        int tt = dst[e];
        int od = outdeg[s];
        float v = emb[(long long)s * D_FEAT + d] * rsqrtf((float)(od > 1 ? od : 1));
        atomicAdd(&out[(long long)tt * D_FEAT + d], v);
    }
}

__global__ void fb_scale(float* __restrict__ out, const int* __restrict__ indeg,
                         long long n_elems) {
    long long i = (long long)blockIdx.x * blockDim.x + threadIdx.x;
    long long stride = (long long)gridDim.x * blockDim.x;
    for (long long j = i; j < n_elems; j += stride) {
        int id = indeg[(int)(j >> 6)];
        out[j] *= rsqrtf((float)(id > 1 ? id : 1));
    }
}

extern "C" void kernel_launch(void* const* d_in, const int* in_sizes, int n_in,
                              void* d_out, int out_size, void* d_ws, size_t ws_size,
                              hipStream_t stream) {
    const float* emb = (const float*)d_in[0];
    const int* src = (const int*)d_in[1];
    const int* dst = (const int*)d_in[2];
    const int n_nodes = in_sizes[0] / D_FEAT;
    const int n_edges = in_sizes[1];
    float* out = (float*)d_out;
    const int block = 256;
    const int nb = (n_nodes + NPB - 1) / NPB;

    // workspace layout (ints)
    float* oscale = (float*)d_ws;                    // N
    float* iscale = oscale + n_nodes;                // N
    int* dbcnt8 = (int*)(iscale + n_nodes);          // 8*NBMAX  (dbcnt8+sbcnt8 contiguous)
    int* sbcnt8 = dbcnt8 + 8 * NBMAX;                // 8*NBMAX
    int* dbstart = sbcnt8 + 8 * NBMAX;               // NBMAX+1
    int* gcursor = dbstart + NBMAX + 1;              // NBMAX
    int* sbstart = gcursor + NBMAX;                  // NBMAX+1
    int* scursor = sbstart + NBMAX + 1;              // NBMAX
    int* starts = scursor + NBMAX;                   // N+1
    int* arrA = starts + n_nodes + 1;                // E
    int* arrB = arrA + n_edges;                      // E
    unsigned char* arrS = (unsigned char*)arrB;      // E bytes, lifetime before arrB writes
    size_t need = ((size_t)3 * n_nodes + 16 * NBMAX + 2 * (NBMAX + 1) + 2 * NBMAX + 1
                   + 2 * (size_t)n_edges) * sizeof(int);

    if (ws_size >= need && nb <= NBMAX) {
        zero_ints<<<32, block, 0, stream>>>(dbcnt8, 16 * NBMAX);
        bcnt_kernel<<<128, block, 0, stream>>>(src, dst, n_edges, dbcnt8, sbcnt8);
        scan2_kernel<<<1, NBMAX, 0, stream>>>(dbcnt8, sbcnt8, dbstart, gcursor,
                                              sbstart, scursor);
        int pblocks = (n_edges + CHUNK - 1) / CHUNK;
        partition_kernel<<<pblocks, 256, 0, stream>>>(src, dst, n_edges, gcursor, arrA);
        spartition_kernel<<<pblocks, 256, 0, stream>>>(src, n_edges, scursor, arrS);
        src_count_kernel<<<nb, 256, 0, stream>>>(arrS, sbstart, oscale, n_nodes);
        bucket_sort_kernel<<<nb, 256, 0, stream>>>(arrA, dbstart, arrB, starts,
                                                   iscale, n_nodes, n_edges);
        aggregate_kernel<<<(n_nodes + 3) / 4, block, 0, stream>>>(emb, arrB, starts,
                                                                  oscale, iscale, out, n_nodes);
    } else {
        int* foutdeg = (int*)d_ws;
        int* findeg = foutdeg + n_nodes;
        long long n_out = (long long)n_nodes * D_FEAT;
        fb_zero<<<2048, block, 0, stream>>>(out, n_out, foutdeg, 2 * n_nodes);
        fb_degree<<<2048, block, 0, stream>>>(src, dst, n_edges, foutdeg, findeg);
        fb_scatter<<<2048, block, 0, stream>>>(emb, src, dst, foutdeg, out, n_edges);
        fb_scale<<<2048, block, 0, stream>>>(out, findeg, n_out);
    }
}

// Round 6
// 164.814 us; speedup vs baseline: 5.2521x; 1.0666x over previous
//
#include <hip/hip_runtime.h>
#include <hip/hip_fp16.h>

#define D_FEAT 64
#define NPB 128            // nodes per bucket (node >> 7)
#define NBMAX 1024         // padded bucket count (pow2 for scan)
#define CHUNK 4096         // edges per partition block
#define EPT 16             // CHUNK / 256

// ---------------- zero ----------------
__global__ void zero_ints(int* __restrict__ p, int n) {
    int i = blockIdx.x * blockDim.x + threadIdx.x;
    int stride = gridDim.x * blockDim.x;
    for (int j = i; j < n; j += stride) p[j] = 0;
}

// ---------------- bucket counts for BOTH sides (LDS hist, split-copy flush) -------
__global__ __launch_bounds__(256) void bcnt_kernel(
        const int* __restrict__ src, const int* __restrict__ dst, int n_edges,
        int* __restrict__ dbcnt8, int* __restrict__ sbcnt8) {
    __shared__ int ld[NBMAX];
    __shared__ int ls[NBMAX];
    int t = threadIdx.x;
    for (int i = t; i < NBMAX; i += 256) { ld[i] = 0; ls[i] = 0; }
    __syncthreads();
    int i0 = blockIdx.x * blockDim.x + t;
    int stride = gridDim.x * blockDim.x;
    for (int e = i0; e < n_edges; e += stride) {
        atomicAdd(&ld[dst[e] >> 7], 1);
        atomicAdd(&ls[src[e] >> 7], 1);
    }
    __syncthreads();
    int* dmy = dbcnt8 + (blockIdx.x & 7) * NBMAX;
    int* smy = sbcnt8 + (blockIdx.x & 7) * NBMAX;
    for (int i = t; i < NBMAX; i += 256) {
        if (ld[i]) atomicAdd(&dmy[i], ld[i]);
        if (ls[i]) atomicAdd(&smy[i], ls[i]);
    }
}

// ---------------- dual exclusive scan (one block, 1024 threads) ----------------
__global__ void scan2_kernel(const int* __restrict__ dbcnt8, const int* __restrict__ sbcnt8,
                             int* __restrict__ dbstart, int* __restrict__ gcursor,
                             int* __restrict__ sbstart, int* __restrict__ scursor) {
    __shared__ int s[NBMAX];
    int t = threadIdx.x;
    int v = 0;
    #pragma unroll
    for (int c = 0; c < 8; ++c) v += dbcnt8[c * NBMAX + t];
    s[t] = v;
    __syncthreads();
    for (int off = 1; off < NBMAX; off <<= 1) {
        int x = (t >= off) ? s[t - off] : 0;
        __syncthreads();
        s[t] += x;
        __syncthreads();
    }
    int ex = s[t] - v;
    dbstart[t] = ex;
    gcursor[t] = ex;
    if (t == NBMAX - 1) dbstart[NBMAX] = ex + v;
    __syncthreads();
    int v2 = 0;
    #pragma unroll
    for (int c = 0; c < 8; ++c) v2 += sbcnt8[c * NBMAX + t];
    s[t] = v2;
    __syncthreads();
    for (int off = 1; off < NBMAX; off <<= 1) {
        int x = (t >= off) ? s[t - off] : 0;
        __syncthreads();
        s[t] += x;
        __syncthreads();
    }
    int ex2 = s[t] - v2;
    sbstart[t] = ex2;
    scursor[t] = ex2;
    if (t == NBMAX - 1) sbstart[NBMAX] = ex2 + v2;
}

// ---------------- dst partition: pk = (src<<7)|(dst&127), bucket dst>>7 ----------
__global__ __launch_bounds__(256) void partition_kernel(
        const int* __restrict__ src, const int* __restrict__ dst, int n_edges,
        int* __restrict__ gcursor, int* __restrict__ arrA) {
    __shared__ int lhist[NBMAX];
    __shared__ int lstart[NBMAX];
    __shared__ int ldelta[NBMAX];
    __shared__ int lcur[NBMAX];
    __shared__ int part[256];
    __shared__ int pkLDS[CHUNK];
    __shared__ unsigned short bktLDS[CHUNK];

    int t = threadIdx.x;
    long long cbase = (long long)blockIdx.x * CHUNK;
    int cnt = n_edges - cbase < CHUNK ? (int)(n_edges - cbase) : CHUNK;

    for (int i = t; i < NBMAX; i += 256) lhist[i] = 0;
    __syncthreads();

    int ssrc[EPT], sdst[EPT];
    #pragma unroll
    for (int i = 0; i < EPT; ++i) {
        long long e = cbase + t + i * 256;
        if (e < n_edges) {
            ssrc[i] = src[e];
            sdst[i] = dst[e];
            atomicAdd(&lhist[sdst[i] >> 7], 1);
        } else {
            sdst[i] = -1;
        }
    }
    __syncthreads();

    int b0 = 4 * t;
    int h0 = lhist[b0], h1 = lhist[b0 + 1], h2 = lhist[b0 + 2], h3 = lhist[b0 + 3];
    int tot = h0 + h1 + h2 + h3;
    part[t] = tot;
    __syncthreads();
    for (int off = 1; off < 256; off <<= 1) {
        int x = (t >= off) ? part[t - off] : 0;
        __syncthreads();
        part[t] += x;
        __syncthreads();
    }
    int ex = part[t] - tot;
    lstart[b0] = ex;
    lstart[b0 + 1] = ex + h0;
    lstart[b0 + 2] = ex + h0 + h1;
    lstart[b0 + 3] = ex + h0 + h1 + h2;
    __syncthreads();

    for (int b = t; b < NBMAX; b += 256) {
        lcur[b] = lstart[b];
        int c = lhist[b];
        if (c > 0) {
            int g = atomicAdd(&gcursor[b], c);
            ldelta[b] = g - lstart[b];
        }
    }
    __syncthreads();

    #pragma unroll
    for (int i = 0; i < EPT; ++i) {
        if (sdst[i] >= 0) {
            int b = sdst[i] >> 7;
            int slot = atomicAdd(&lcur[b], 1);
            pkLDS[slot] = (ssrc[i] << 7) | (sdst[i] & 127);
            bktLDS[slot] = (unsigned short)b;
        }
    }
    __syncthreads();

    for (int j = t; j < cnt; j += 256) {
        int b = bktLDS[j];
        arrA[j + ldelta[b]] = pkLDS[j];
    }
}

// ---------------- src partition: bytes (src&127), bucket src>>7 ----------------
__global__ __launch_bounds__(256) void spartition_kernel(
        const int* __restrict__ src, int n_edges,
        int* __restrict__ scursor, unsigned char* __restrict__ arrS) {
    __shared__ int lhist[NBMAX];
    __shared__ int lstart[NBMAX];
    __shared__ int ldelta[NBMAX];
    __shared__ int lcur[NBMAX];
    __shared__ int part[256];
    __shared__ unsigned char stg[CHUNK];
    __shared__ unsigned short bktLDS[CHUNK];

    int t = threadIdx.x;
    long long cbase = (long long)blockIdx.x * CHUNK;
    int cnt = n_edges - cbase < CHUNK ? (int)(n_edges - cbase) : CHUNK;

    for (int i = t; i < NBMAX; i += 256) lhist[i] = 0;
    __syncthreads();

    int ssrc[EPT];
    #pragma unroll
    for (int i = 0; i < EPT; ++i) {
        long long e = cbase + t + i * 256;
        if (e < n_edges) {
            ssrc[i] = src[e];
            atomicAdd(&lhist[ssrc[i] >> 7], 1);
        } else {
            ssrc[i] = -1;
        }
    }
    __syncthreads();

    int b0 = 4 * t;
    int h0 = lhist[b0], h1 = lhist[b0 + 1], h2 = lhist[b0 + 2], h3 = lhist[b0 + 3];
    int tot = h0 + h1 + h2 + h3;
    part[t] = tot;
    __syncthreads();
    for (int off = 1; off < 256; off <<= 1) {
        int x = (t >= off) ? part[t - off] : 0;
        __syncthreads();
        part[t] += x;
        __syncthreads();
    }
    int ex = part[t] - tot;
    lstart[b0] = ex;
    lstart[b0 + 1] = ex + h0;
    lstart[b0 + 2] = ex + h0 + h1;
    lstart[b0 + 3] = ex + h0 + h1 + h2;
    __syncthreads();

    for (int b = t; b < NBMAX; b += 256) {
        lcur[b] = lstart[b];
        int c = lhist[b];
        if (c > 0) {
            int g = atomicAdd(&scursor[b], c);
            ldelta[b] = g - lstart[b];
        }
    }
    __syncthreads();

    #pragma unroll
    for (int i = 0; i < EPT; ++i) {
        if (ssrc[i] >= 0) {
            int b = ssrc[i] >> 7;
            int slot = atomicAdd(&lcur[b], 1);
            stg[slot] = (unsigned char)(ssrc[i] & 127);
            bktLDS[slot] = (unsigned short)b;
        }
    }
    __syncthreads();

    for (int j = t; j < cnt; j += 256) {
        int b = bktLDS[j];
        arrS[j + ldelta[b]] = stg[j];
    }
}

// ---------------- per-bucket out-degree -> oscale (no global atomics) -----------
__global__ __launch_bounds__(256) void src_count_kernel(
        const unsigned char* __restrict__ arrS, const int* __restrict__ sbstart,
        float* __restrict__ oscale, int n_nodes) {
    __shared__ int lh[NPB];
    int b = blockIdx.x, t = threadIdx.x;
    int s = sbstart[b], e = sbstart[b + 1];
    if (t < NPB) lh[t] = 0;
    __syncthreads();
    for (int i = s + t; i < e; i += 256) atomicAdd(&lh[arrS[i]], 1);
    __syncthreads();
    if (t < NPB) {
        int node = b * NPB + t;
        if (node < n_nodes) {
            int od = lh[t];
            oscale[node] = rsqrtf((float)(od > 1 ? od : 1));
        }
    }
}

// ---------------- per-bucket counting sort -> CSR ----------------
__global__ __launch_bounds__(256) void bucket_sort_kernel(
        const int* __restrict__ arrA, const int* __restrict__ bstart,
        int* __restrict__ arrB, int* __restrict__ starts,
        float* __restrict__ iscale, int n_nodes, int n_edges) {
    __shared__ int lh[NPB];
    __shared__ int lst[NPB];
    __shared__ int lcur[NPB];
    int b = blockIdx.x, t = threadIdx.x;
    int s = bstart[b], e = bstart[b + 1];
    int cnt = e - s;
    for (int i = t; i < NPB; i += 256) lh[i] = 0;
    __syncthreads();
    for (int i = t; i < cnt; i += 256) atomicAdd(&lh[arrA[s + i] & 127], 1);
    __syncthreads();
    if (t < 64) {
        int l0 = lh[t], l1 = lh[t + 64];
        int a = l0;
        for (int off = 1; off < 64; off <<= 1) { int y = __shfl_up(a, off); if (t >= off) a += y; }
        int tot0 = __shfl(a, 63);
        int c = l1;
        for (int off = 1; off < 64; off <<= 1) { int y = __shfl_up(c, off); if (t >= off) c += y; }
        lst[t] = a - l0;
        lst[t + 64] = tot0 + c - l1;
    }
    __syncthreads();
    int nbase = b * NPB;
    for (int i = t; i < NPB; i += 256) {
        lcur[i] = lst[i];
        int node = nbase + i;
        if (node < n_nodes) {
            starts[node] = s + lst[i];
            int id = lh[i];
            iscale[node] = rsqrtf((float)(id > 1 ? id : 1));
        }
    }
    if (b == 0 && t == 0) starts[n_nodes] = n_edges;
    __syncthreads();
    for (int i = t; i < cnt; i += 256) {
        int v = arrA[s + i];
        int slot = s + atomicAdd(&lcur[v & 127], 1);
        arrB[slot] = v >> 7;
    }
}

// ---------------- h prepass: h[node][d] = fp16(emb * oscale); row n_nodes = 0 ----
__global__ void h_prepass_kernel(const float4* __restrict__ emb4,
                                 const float* __restrict__ oscale,
                                 uint2* __restrict__ h2, int n_total, int n_nodes) {
    int i = blockIdx.x * blockDim.x + threadIdx.x;
    int stride = gridDim.x * blockDim.x;
    for (int j = i; j < n_total; j += stride) {
        int node = j >> 4;
        uint2 r;
        if (node < n_nodes) {
            float s = oscale[node];
            float4 v = emb4[j];
            __half2 a = __floats2half2_rn(v.x * s, v.y * s);
            __half2 b = __floats2half2_rn(v.z * s, v.w * s);
            union { __half2 h; unsigned int u; } ua, ub;
            ua.h = a; ub.h = b;
            r.x = ua.u; r.y = ub.u;
        } else {
            r.x = 0; r.y = 0;
        }
        h2[j] = r;
    }
}

// ---------------- aggregate (fp16 rows): 4 groups x 16 lanes, 16 edges/iter ------
__global__ __launch_bounds__(256) void agg_half_kernel(
        const uint2* __restrict__ h2, const int* __restrict__ arrB,
        const int* __restrict__ starts, const float* __restrict__ iscale,
        float* __restrict__ out, int n_nodes) {
    int node = blockIdx.x * 4 + (threadIdx.x >> 6);
    if (node >= n_nodes) return;
    int L = threadIdx.x & 63;
    int g = L >> 4;        // edge group 0..3
    int c = L & 15;        // uint2 chunk (4 halfs) within row
    int e0 = starts[node];
    int e1 = starts[node + 1];
    float ax = 0.f, ay = 0.f, az = 0.f, aw = 0.f;
    for (int e = e0; e < e1; e += 16) {
        int ea = e + g, eb = ea + 4, ec = ea + 8, ed = ea + 12;
        int sa = (ea < e1) ? arrB[ea] : n_nodes;
        int sb = (eb < e1) ? arrB[eb] : n_nodes;
        int sc = (ec < e1) ? arrB[ec] : n_nodes;
        int sd = (ed < e1) ? arrB[ed] : n_nodes;
        uint2 va = h2[sa * 16 + c];
        uint2 vb = h2[sb * 16 + c];
        uint2 vc = h2[sc * 16 + c];
        uint2 vd = h2[sd * 16 + c];
        union { unsigned int u; __half2 h; } w;
        float2 f;
        w.u = va.x; f = __half22float2(w.h); ax += f.x; ay += f.y;
        w.u = va.y; f = __half22float2(w.h); az += f.x; aw += f.y;
        w.u = vb.x; f = __half22float2(w.h); ax += f.x; ay += f.y;
        w.u = vb.y; f = __half22float2(w.h); az += f.x; aw += f.y;
        w.u = vc.x; f = __half22float2(w.h); ax += f.x; ay += f.y;
        w.u = vc.y; f = __half22float2(w.h); az += f.x; aw += f.y;
        w.u = vd.x; f = __half22float2(w.h); ax += f.x; ay += f.y;
        w.u = vd.y; f = __half22float2(w.h); az += f.x; aw += f.y;
    }
    ax += __shfl_xor(ax, 16); ay += __shfl_xor(ay, 16);
    az += __shfl_xor(az, 16); aw += __shfl_xor(aw, 16);
    ax += __shfl_xor(ax, 32); ay += __shfl_xor(ay, 32);
    az += __shfl_xor(az, 32); aw += __shfl_xor(aw, 32);
    if (g == 0) {
        float is = iscale[node];
        float4 r;
        r.x = ax * is; r.y = ay * is; r.z = az * is; r.w = aw * is;
        // lanes 0..15 hold the two half-chunks of the row; chunk c
        float2* o2 = (float2*)&r;
        ((float4*)out)[node * 16 + c] = r;
        (void)o2;
    }
}

// ---------------- aggregate (fp32 fallback, round-5 proven) ----------------
__global__ __launch_bounds__(256) void agg_f32_kernel(
        const float* __restrict__ emb, const int* __restrict__ arrB,
        const int* __restrict__ starts, const float* __restrict__ oscale,
        const float* __restrict__ iscale, float* __restrict__ out, int n_nodes) {
    int node = blockIdx.x * 4 + (threadIdx.x >> 6);
    if (node >= n_nodes) return;
    int L = threadIdx.x & 63;
    int g = L >> 4;
    int c = L & 15;
    int e0 = starts[node];
    int e1 = starts[node + 1];
    const float4* emb4 = (const float4*)emb;
    float ax = 0.f, ay = 0.f, az = 0.f, aw = 0.f;
    for (int e = e0; e < e1; e += 8) {
        int ea = e + g, eb = e + 4 + g;
        bool oka = ea < e1, okb = eb < e1;
        int sa = oka ? arrB[ea] : 0;
        int sb = okb ? arrB[eb] : 0;
        float fa = oka ? oscale[sa] : 0.f;
        float fb = okb ? oscale[sb] : 0.f;
        float4 va = emb4[sa * 16 + c];
        float4 vb = emb4[sb * 16 + c];
        ax += va.x * fa; ay += va.y * fa; az += va.z * fa; aw += va.w * fa;
        ax += vb.x * fb; ay += vb.y * fb; az += vb.z * fb; aw += vb.w * fb;
    }
    ax += __shfl_xor(ax, 16); ay += __shfl_xor(ay, 16);
    az += __shfl_xor(az, 16); aw += __shfl_xor(aw, 16);
    ax += __shfl_xor(ax, 32); ay += __shfl_xor(ay, 32);
    az += __shfl_xor(az, 32); aw += __shfl_xor(aw, 32);
    if (g == 0) {
        float is = iscale[node];
        float4 r;
        r.x = ax * is; r.y = ay * is; r.z = az * is; r.w = aw * is;
        ((float4*)out)[node * 16 + c] = r;
    }
}

// ---------------- fallback: atomic scatter path (tiny ws) ----------------
__global__ void fb_zero(float* __restrict__ out, long long n_out,
                        int* __restrict__ deg, int n_deg) {
    long long i = (long long)blockIdx.x * blockDim.x + threadIdx.x;
    long long stride = (long long)gridDim.x * blockDim.x;
    for (long long j = i; j < n_out; j += stride) out[j] = 0.0f;
    for (long long j = i; j < n_deg; j += stride) deg[j] = 0;
}

__global__ void fb_degree(const int* __restrict__ src, const int* __restrict__ dst,
                          int n_edges, int* __restrict__ outdeg, int* __restrict__ indeg) {
    int i = blockIdx.x * blockDim.x + threadIdx.x;
    int stride = gridDim.x * blockDim.x;
    for (int e = i; e < n_edges; e += stride) {
        atomicAdd(&outdeg[src[e]], 1);
        atomicAdd(&indeg[dst[e]], 1);
    }
}

__global__ void fb_scatter(const float* __restrict__ emb,
                           const int* __restrict__ src, const int* __restrict__ dst,
                           const int* __restrict__ outdeg,
                           float* __restrict__ out, int n_edges) {
    const int epb = blockDim.x >> 6;
    const int d = threadIdx.x & 63;
    long long e0 = (long long)blockIdx.x * epb + (threadIdx.x >> 6);
    long long estride = (long long)gridDim.x * epb;
    for (long long e = e0; e < n_edges; e += estride) {
        int s = src[e];
        int tt = dst[e];
        int od = outdeg[s];
        float v = emb[(long long)s * D_FEAT + d] * rsqrtf((float)(od > 1 ? od : 1));
        atomicAdd(&out[(long long)tt * D_FEAT + d], v);
    }
}

__global__ void fb_scale(float* __restrict__ out, const int* __restrict__ indeg,
                         long long n_elems) {
    long long i = (long long)blockIdx.x * blockDim.x + threadIdx.x;
    long long stride = (long long)gridDim.x * blockDim.x;
    for (long long j = i; j < n_elems; j += stride) {
        int id = indeg[(int)(j >> 6)];
        out[j] *= rsqrtf((float)(id > 1 ? id : 1));
    }
}

extern "C" void kernel_launch(void* const* d_in, const int* in_sizes, int n_in,
                              void* d_out, int out_size, void* d_ws, size_t ws_size,
                              hipStream_t stream) {
    const float* emb = (const float*)d_in[0];
    const int* src = (const int*)d_in[1];
    const int* dst = (const int*)d_in[2];
    const int n_nodes = in_sizes[0] / D_FEAT;
    const int n_edges = in_sizes[1];
    float* out = (float*)d_out;
    const int block = 256;
    const int nb = (n_nodes + NPB - 1) / NPB;
    const int K = NBMAX;

    // layout (ints): oscale | iscale | dbcnt8 | sbcnt8 | dbstart | gcursor |
    //                sbstart | scursor | starts | arrB | arrA/h
    float* oscale = (float*)d_ws;                    // N
    float* iscale = oscale + n_nodes;                // N
    int* dbcnt8 = (int*)(iscale + n_nodes);          // 8K
    int* sbcnt8 = dbcnt8 + 8 * K;                    // 8K
    int* dbstart = sbcnt8 + 8 * K;                   // K+1
    int* gcursor = dbstart + K + 1;                  // K
    int* sbstart = gcursor + K;                      // K+1
    int* scursor = sbstart + K + 1;                  // K
    int* starts = scursor + K;                       // N+1
    int* arrB = starts + n_nodes + 1;                // E ints
    int* arrA = arrB + n_edges;                      // E ints (dead after bucket_sort)
    unsigned char* arrS = (unsigned char*)arrB;      // E bytes, consumed before arrB write
    uint2* h2 = (uint2*)arrA;                        // (N+1)*16 uint2, written after bucket_sort

    size_t common_ints = (size_t)2 * n_nodes + 16 * (size_t)K + 2 * (K + 1) + 2 * K
                         + (size_t)n_nodes + 1 + (size_t)n_edges;
    size_t h_ints = (size_t)(n_nodes + 1) * 32;      // (N+1)*128 bytes
    size_t arrA_ints = (size_t)n_edges;
    size_t need_small = (common_ints + arrA_ints) * sizeof(int);
    size_t big_tail = (h_ints > arrA_ints) ? h_ints : arrA_ints;
    size_t need_big = (common_ints + big_tail) * sizeof(int);

    if (ws_size >= need_small && nb <= K) {
        bool big = (ws_size >= need_big);
        zero_ints<<<32, block, 0, stream>>>(dbcnt8, 16 * K);
        bcnt_kernel<<<128, block, 0, stream>>>(src, dst, n_edges, dbcnt8, sbcnt8);
        scan2_kernel<<<1, K, 0, stream>>>(dbcnt8, sbcnt8, dbstart, gcursor,
                                          sbstart, scursor);
        int pblocks = (n_edges + CHUNK - 1) / CHUNK;
        partition_kernel<<<pblocks, 256, 0, stream>>>(src, dst, n_edges, gcursor, arrA);
        spartition_kernel<<<pblocks, 256, 0, stream>>>(src, n_edges, scursor, arrS);
        src_count_kernel<<<nb, 256, 0, stream>>>(arrS, sbstart, oscale, n_nodes);
        bucket_sort_kernel<<<nb, 256, 0, stream>>>(arrA, dbstart, arrB, starts,
                                                   iscale, n_nodes, n_edges);
        if (big) {
            int n_total = (n_nodes + 1) * 16;        // uint2 count (incl. zero row)
            h_prepass_kernel<<<2048, block, 0, stream>>>((const float4*)emb, oscale,
                                                         h2, n_total, n_nodes);
            agg_half_kernel<<<(n_nodes + 3) / 4, block, 0, stream>>>(h2, arrB, starts,
                                                                     iscale, out, n_nodes);
        } else {
            agg_f32_kernel<<<(n_nodes + 3) / 4, block, 0, stream>>>(emb, arrB, starts,
                                                                    oscale, iscale, out, n_nodes);
        }
    } else {
        int* foutdeg = (int*)d_ws;
        int* findeg = foutdeg + n_nodes;
        long long n_out = (long long)n_nodes * D_FEAT;
        fb_zero<<<2048, block, 0, stream>>>(out, n_out, foutdeg, 2 * n_nodes);
        fb_degree<<<2048, block, 0, stream>>>(src, dst, n_edges, foutdeg, findeg);
        fb_scatter<<<2048, block, 0, stream>>>(emb, src, dst, foutdeg, out, n_edges);
        fb_scale<<<2048, block, 0, stream>>>(out, findeg, n_out);
    }
}

// Round 7
// 147.070 us; speedup vs baseline: 5.8858x; 1.1207x over previous
//
#include <hip/hip_runtime.h>
#include <hip/hip_fp16.h>

#define D_FEAT 64
#define NPB 128            // nodes per bucket (node >> 7)
#define NBMAX 1024         // padded bucket count (pow2 for scan)
#define CHUNK 4096         // edges per partition block
#define EPT 16             // CHUNK / 256
#define CAPB 4096          // sortagg LDS edge capacity per bucket

// ---------------- zero ----------------
__global__ void zero_ints(int* __restrict__ p, int n) {
    int i = blockIdx.x * blockDim.x + threadIdx.x;
    int stride = gridDim.x * blockDim.x;
    for (int j = i; j < n; j += stride) p[j] = 0;
}

// ---------------- bucket counts for BOTH sides (LDS hist, split-copy flush) -------
__global__ __launch_bounds__(256) void bcnt_kernel(
        const int* __restrict__ src, const int* __restrict__ dst, int n_edges,
        int* __restrict__ dbcnt8, int* __restrict__ sbcnt8) {
    __shared__ int ld[NBMAX];
    __shared__ int ls[NBMAX];
    int t = threadIdx.x;
    for (int i = t; i < NBMAX; i += 256) { ld[i] = 0; ls[i] = 0; }
    __syncthreads();
    int i0 = blockIdx.x * blockDim.x + t;
    int stride = gridDim.x * blockDim.x;
    for (int e = i0; e < n_edges; e += stride) {
        atomicAdd(&ld[dst[e] >> 7], 1);
        atomicAdd(&ls[src[e] >> 7], 1);
    }
    __syncthreads();
    int* dmy = dbcnt8 + (blockIdx.x & 7) * NBMAX;
    int* smy = sbcnt8 + (blockIdx.x & 7) * NBMAX;
    for (int i = t; i < NBMAX; i += 256) {
        if (ld[i]) atomicAdd(&dmy[i], ld[i]);
        if (ls[i]) atomicAdd(&smy[i], ls[i]);
    }
}

// ---------------- dual exclusive scan (one block, 1024 threads) ----------------
__global__ void scan2_kernel(const int* __restrict__ dbcnt8, const int* __restrict__ sbcnt8,
                             int* __restrict__ dbstart, int* __restrict__ gcursor,
                             int* __restrict__ sbstart, int* __restrict__ scursor) {
    __shared__ int s[NBMAX];
    int t = threadIdx.x;
    int v = 0;
    #pragma unroll
    for (int c = 0; c < 8; ++c) v += dbcnt8[c * NBMAX + t];
    s[t] = v;
    __syncthreads();
    for (int off = 1; off < NBMAX; off <<= 1) {
        int x = (t >= off) ? s[t - off] : 0;
        __syncthreads();
        s[t] += x;
        __syncthreads();
    }
    int ex = s[t] - v;
    dbstart[t] = ex;
    gcursor[t] = ex;
    if (t == NBMAX - 1) dbstart[NBMAX] = ex + v;
    __syncthreads();
    int v2 = 0;
    #pragma unroll
    for (int c = 0; c < 8; ++c) v2 += sbcnt8[c * NBMAX + t];
    s[t] = v2;
    __syncthreads();
    for (int off = 1; off < NBMAX; off <<= 1) {
        int x = (t >= off) ? s[t - off] : 0;
        __syncthreads();
        s[t] += x;
        __syncthreads();
    }
    int ex2 = s[t] - v2;
    sbstart[t] = ex2;
    scursor[t] = ex2;
    if (t == NBMAX - 1) sbstart[NBMAX] = ex2 + v2;
}

// ---------------- fused dual partition: one read of src+dst ----------------
// Phase D: arrA[pk = (src<<7)|(dst&127)] bucketed by dst>>7
// Phase S: arrS[src&127 byte] bucketed by src>>7  (same LDS reused)
__global__ __launch_bounds__(256) void dualpart_kernel(
        const int* __restrict__ src, const int* __restrict__ dst, int n_edges,
        int* __restrict__ gcursor, int* __restrict__ scursor,
        int* __restrict__ arrA, unsigned char* __restrict__ arrS) {
    __shared__ int lhist[NBMAX];
    __shared__ int lstart[NBMAX];
    __shared__ int ldelta[NBMAX];
    __shared__ int lcur[NBMAX];
    __shared__ int part[256];
    __shared__ int pkLDS[CHUNK];
    __shared__ unsigned short bktLDS[CHUNK];

    int t = threadIdx.x;
    long long cbase = (long long)blockIdx.x * CHUNK;
    int cnt = (n_edges - cbase < CHUNK) ? (int)(n_edges - cbase) : CHUNK;

    for (int i = t; i < NBMAX; i += 256) lhist[i] = 0;
    __syncthreads();

    int ssrc[EPT], sdst[EPT];
    #pragma unroll
    for (int i = 0; i < EPT; ++i) {
        long long e = cbase + t + i * 256;
        if (e < n_edges) {
            ssrc[i] = src[e];
            sdst[i] = dst[e];
            atomicAdd(&lhist[sdst[i] >> 7], 1);
        } else {
            ssrc[i] = -1;
            sdst[i] = -1;
        }
    }
    __syncthreads();

    // ---- phase D scan ----
    int b0 = 4 * t;
    int h0 = lhist[b0], h1 = lhist[b0 + 1], h2v = lhist[b0 + 2], h3 = lhist[b0 + 3];
    int tot = h0 + h1 + h2v + h3;
    part[t] = tot;
    __syncthreads();
    for (int off = 1; off < 256; off <<= 1) {
        int x = (t >= off) ? part[t - off] : 0;
        __syncthreads();
        part[t] += x;
        __syncthreads();
    }
    int ex = part[t] - tot;
    lstart[b0] = ex;
    lstart[b0 + 1] = ex + h0;
    lstart[b0 + 2] = ex + h0 + h1;
    lstart[b0 + 3] = ex + h0 + h1 + h2v;
    __syncthreads();
    for (int b = t; b < NBMAX; b += 256) {
        lcur[b] = lstart[b];
        int c = lhist[b];
        if (c > 0) ldelta[b] = atomicAdd(&gcursor[b], c) - lstart[b];
    }
    __syncthreads();
    #pragma unroll
    for (int i = 0; i < EPT; ++i) {
        if (sdst[i] >= 0) {
            int b = sdst[i] >> 7;
            int slot = atomicAdd(&lcur[b], 1);
            pkLDS[slot] = (ssrc[i] << 7) | (sdst[i] & 127);
            bktLDS[slot] = (unsigned short)b;
        }
    }
    __syncthreads();
    for (int j = t; j < cnt; j += 256) {
        int b = bktLDS[j];
        arrA[j + ldelta[b]] = pkLDS[j];
    }
    __syncthreads();

    // ---- phase S (reuse all LDS) ----
    for (int i = t; i < NBMAX; i += 256) lhist[i] = 0;
    __syncthreads();
    #pragma unroll
    for (int i = 0; i < EPT; ++i) {
        if (ssrc[i] >= 0) atomicAdd(&lhist[ssrc[i] >> 7], 1);
    }
    __syncthreads();
    h0 = lhist[b0]; h1 = lhist[b0 + 1]; h2v = lhist[b0 + 2]; h3 = lhist[b0 + 3];
    tot = h0 + h1 + h2v + h3;
    part[t] = tot;
    __syncthreads();
    for (int off = 1; off < 256; off <<= 1) {
        int x = (t >= off) ? part[t - off] : 0;
        __syncthreads();
        part[t] += x;
        __syncthreads();
    }
    ex = part[t] - tot;
    lstart[b0] = ex;
    lstart[b0 + 1] = ex + h0;
    lstart[b0 + 2] = ex + h0 + h1;
    lstart[b0 + 3] = ex + h0 + h1 + h2v;
    __syncthreads();
    for (int b = t; b < NBMAX; b += 256) {
        lcur[b] = lstart[b];
        int c = lhist[b];
        if (c > 0) ldelta[b] = atomicAdd(&scursor[b], c) - lstart[b];
    }
    __syncthreads();
    unsigned char* stg = (unsigned char*)pkLDS;
    #pragma unroll
    for (int i = 0; i < EPT; ++i) {
        if (ssrc[i] >= 0) {
            int b = ssrc[i] >> 7;
            int slot = atomicAdd(&lcur[b], 1);
            stg[slot] = (unsigned char)(ssrc[i] & 127);
            bktLDS[slot] = (unsigned short)b;
        }
    }
    __syncthreads();
    for (int j = t; j < cnt; j += 256) {
        int b = bktLDS[j];
        arrS[j + ldelta[b]] = stg[j];
    }
}

// ---------------- per-bucket out-degree -> oscale ----------------
__global__ __launch_bounds__(256) void src_count_kernel(
        const unsigned char* __restrict__ arrS, const int* __restrict__ sbstart,
        float* __restrict__ oscale, int n_nodes) {
    __shared__ int lh[NPB];
    int b = blockIdx.x, t = threadIdx.x;
    int s = sbstart[b], e = sbstart[b + 1];
    if (t < NPB) lh[t] = 0;
    __syncthreads();
    for (int i = s + t; i < e; i += 256) atomicAdd(&lh[arrS[i]], 1);
    __syncthreads();
    if (t < NPB) {
        int node = b * NPB + t;
        if (node < n_nodes) {
            int od = lh[t];
            oscale[node] = rsqrtf((float)(od > 1 ? od : 1));
        }
    }
}

// ---------------- h prepass: h[node][d] = fp16(emb * oscale); row n_nodes = 0 ----
__global__ void h_prepass_kernel(const float4* __restrict__ emb4,
                                 const float* __restrict__ oscale,
                                 uint2* __restrict__ h2, int n_total, int n_nodes) {
    int i = blockIdx.x * blockDim.x + threadIdx.x;
    int stride = gridDim.x * blockDim.x;
    for (int j = i; j < n_total; j += stride) {
        int node = j >> 4;
        uint2 r;
        if (node < n_nodes) {
            float s = oscale[node];
            float4 v = emb4[j];
            __half2 a = __floats2half2_rn(v.x * s, v.y * s);
            __half2 b = __floats2half2_rn(v.z * s, v.w * s);
            union { __half2 h; unsigned int u; } ua, ub;
            ua.h = a; ub.h = b;
            r.x = ua.u; r.y = ub.u;
        } else {
            r.x = 0; r.y = 0;
        }
        h2[j] = r;
    }
}

// ---------------- fused sort + aggregate: one block per dst bucket ----------------
__global__ __launch_bounds__(512) void sortagg_kernel(
        const uint2* __restrict__ h2, const int* __restrict__ arrA,
        const int* __restrict__ dbstart, float* __restrict__ out, int n_nodes) {
    __shared__ int lh[NPB];
    __shared__ int lst[NPB];
    __shared__ int lcur[NPB];
    __shared__ int srcS[CAPB];
    int b = blockIdx.x, t = threadIdx.x;
    int s = dbstart[b], e = dbstart[b + 1];
    int cnt = e - s;

    if (t < NPB) lh[t] = 0;
    __syncthreads();
    for (int i = t; i < cnt; i += 512) atomicAdd(&lh[arrA[s + i] & 127], 1);
    __syncthreads();
    if (t < 64) {
        int l0 = lh[t], l1 = lh[t + 64];
        int a = l0;
        for (int off = 1; off < 64; off <<= 1) { int y = __shfl_up(a, off); if (t >= off) a += y; }
        int tot0 = __shfl(a, 63);
        int c = l1;
        for (int off = 1; off < 64; off <<= 1) { int y = __shfl_up(c, off); if (t >= off) c += y; }
        lst[t] = a - l0;
        lst[t + 64] = tot0 + c - l1;
    }
    __syncthreads();
    if (t < NPB) lcur[t] = lst[t];
    __syncthreads();
    bool fit = (cnt <= CAPB);
    if (fit) {
        for (int i = t; i < cnt; i += 512) {
            int v = arrA[s + i];
            int slot = atomicAdd(&lcur[v & 127], 1);
            srcS[slot] = v >> 7;
        }
    }
    __syncthreads();

    int w = t >> 6, L = t & 63, g = L >> 4, c = L & 15;
    int nbase = b * NPB;
    union { unsigned int u; __half2 h; } uc;
    for (int nl = w * 16; nl < w * 16 + 16; ++nl) {
        int node = nbase + nl;
        if (node >= n_nodes) break;
        int st = lst[nl];
        int deg = lh[nl];
        int en = st + deg;
        float ax = 0.f, ay = 0.f, az = 0.f, aw = 0.f;
        if (fit) {
            for (int eidx = st; eidx < en; eidx += 16) {
                int ea = eidx + g, eb = ea + 4, ec = ea + 8, ed = ea + 12;
                int sa = (ea < en) ? srcS[ea] : n_nodes;
                int sb = (eb < en) ? srcS[eb] : n_nodes;
                int sc = (ec < en) ? srcS[ec] : n_nodes;
                int sd = (ed < en) ? srcS[ed] : n_nodes;
                uint2 va = h2[sa * 16 + c];
                uint2 vb = h2[sb * 16 + c];
                uint2 vc = h2[sc * 16 + c];
                uint2 vd = h2[sd * 16 + c];
                float2 f;
                uc.u = va.x; f = __half22float2(uc.h); ax += f.x; ay += f.y;
                uc.u = va.y; f = __half22float2(uc.h); az += f.x; aw += f.y;
                uc.u = vb.x; f = __half22float2(uc.h); ax += f.x; ay += f.y;
                uc.u = vb.y; f = __half22float2(uc.h); az += f.x; aw += f.y;
                uc.u = vc.x; f = __half22float2(uc.h); ax += f.x; ay += f.y;
                uc.u = vc.y; f = __half22float2(uc.h); az += f.x; aw += f.y;
                uc.u = vd.x; f = __half22float2(uc.h); ax += f.x; ay += f.y;
                uc.u = vd.y; f = __half22float2(uc.h); az += f.x; aw += f.y;
            }
        } else {
            // oversized bucket: scan segment from global (correctness fallback)
            for (int i2 = g; i2 < cnt; i2 += 4) {
                int v = arrA[s + i2];
                if ((v & 127) == nl) {
                    int sa = v >> 7;
                    uint2 va = h2[sa * 16 + c];
                    float2 f;
                    uc.u = va.x; f = __half22float2(uc.h); ax += f.x; ay += f.y;
                    uc.u = va.y; f = __half22float2(uc.h); az += f.x; aw += f.y;
                }
            }
        }
        ax += __shfl_xor(ax, 16); ay += __shfl_xor(ay, 16);
        az += __shfl_xor(az, 16); aw += __shfl_xor(aw, 16);
        ax += __shfl_xor(ax, 32); ay += __shfl_xor(ay, 32);
        az += __shfl_xor(az, 32); aw += __shfl_xor(aw, 32);
        if (g == 0) {
            float is = rsqrtf((float)(deg > 1 ? deg : 1));
            float4 r;
            r.x = ax * is; r.y = ay * is; r.z = az * is; r.w = aw * is;
            ((float4*)out)[node * 16 + c] = r;
        }
    }
}

// ---------------- fallback: atomic scatter path (tiny ws) ----------------
__global__ void fb_zero(float* __restrict__ out, long long n_out,
                        int* __restrict__ deg, int n_deg) {
    long long i = (long long)blockIdx.x * blockDim.x + threadIdx.x;
    long long stride = (long long)gridDim.x * blockDim.x;
    for (long long j = i; j < n_out; j += stride) out[j] = 0.0f;
    for (long long j = i; j < n_deg; j += stride) deg[j] = 0;
}

__global__ void fb_degree(const int* __restrict__ src, const int* __restrict__ dst,
                          int n_edges, int* __restrict__ outdeg, int* __restrict__ indeg) {
    int i = blockIdx.x * blockDim.x + threadIdx.x;
    int stride = gridDim.x * blockDim.x;
    for (int e = i; e < n_edges; e += stride) {
        atomicAdd(&outdeg[src[e]], 1);
        atomicAdd(&indeg[dst[e]], 1);
    }
}

__global__ void fb_scatter(const float* __restrict__ emb,
                           const int* __restrict__ src, const int* __restrict__ dst,
                           const int* __restrict__ outdeg,
                           float* __restrict__ out, int n_edges) {
    const int epb = blockDim.x >> 6;
    const int d = threadIdx.x & 63;
    long long e0 = (long long)blockIdx.x * epb + (threadIdx.x >> 6);
    long long estride = (long long)gridDim.x * epb;
    for (long long e = e0; e < n_edges; e += estride) {
        int s = src[e];
        int tt = dst[e];
        int od = outdeg[s];
        float v = emb[(long long)s * D_FEAT + d] * rsqrtf((float)(od > 1 ? od : 1));
        atomicAdd(&out[(long long)tt * D_FEAT + d], v);
    }
}

__global__ void fb_scale(float* __restrict__ out, const int* __restrict__ indeg,
                         long long n_elems) {
    long long i = (long long)blockIdx.x * blockDim.x + threadIdx.x;
    long long stride = (long long)gridDim.x * blockDim.x;
    for (long long j = i; j < n_elems; j += stride) {
        int id = indeg[(int)(j >> 6)];
        out[j] *= rsqrtf((float)(id > 1 ? id : 1));
    }
}

extern "C" void kernel_launch(void* const* d_in, const int* in_sizes, int n_in,
                              void* d_out, int out_size, void* d_ws, size_t ws_size,
                              hipStream_t stream) {
    const float* emb = (const float*)d_in[0];
    const int* src = (const int*)d_in[1];
    const int* dst = (const int*)d_in[2];
    const int n_nodes = in_sizes[0] / D_FEAT;
    const int n_edges = in_sizes[1];
    float* out = (float*)d_out;
    const int block = 256;
    const int nb = (n_nodes + NPB - 1) / NPB;
    const int K = NBMAX;

    // layout (ints): oscale | dbcnt8 | sbcnt8 | dbstart | gcursor | sbstart |
    //                scursor | arrA | region{arrS bytes -> h2}
    float* oscale = (float*)d_ws;                    // N
    int* dbcnt8 = (int*)(oscale + n_nodes);          // 8K
    int* sbcnt8 = dbcnt8 + 8 * K;                    // 8K
    int* dbstart = sbcnt8 + 8 * K;                   // K+1
    int* gcursor = dbstart + K + 1;                  // K
    int* sbstart = gcursor + K;                      // K+1
    int* scursor = sbstart + K + 1;                  // K
    int* arrA = scursor + K;                         // E
    int* region = arrA + n_edges;                    // max(E/4, (N+1)*32) ints
    unsigned char* arrS = (unsigned char*)region;    // E bytes (dead after src_count)
    uint2* h2 = (uint2*)region;                      // (N+1)*16 uint2 (written after)

    size_t region_ints = (size_t)(n_nodes + 1) * 32;
    size_t arrS_ints = ((size_t)n_edges + 3) / 4;
    if (arrS_ints > region_ints) region_ints = arrS_ints;
    size_t need = ((size_t)n_nodes + 16 * (size_t)K + 2 * (size_t)(K + 1) + 2 * (size_t)K
                   + (size_t)n_edges + region_ints) * sizeof(int);

    if (ws_size >= need && nb <= K) {
        zero_ints<<<32, block, 0, stream>>>(dbcnt8, 16 * K);
        bcnt_kernel<<<128, block, 0, stream>>>(src, dst, n_edges, dbcnt8, sbcnt8);
        scan2_kernel<<<1, K, 0, stream>>>(dbcnt8, sbcnt8, dbstart, gcursor,
                                          sbstart, scursor);
        int pblocks = (n_edges + CHUNK - 1) / CHUNK;
        dualpart_kernel<<<pblocks, 256, 0, stream>>>(src, dst, n_edges, gcursor,
                                                     scursor, arrA, arrS);
        src_count_kernel<<<nb, 256, 0, stream>>>(arrS, sbstart, oscale, n_nodes);
        int n_total = (n_nodes + 1) * 16;
        h_prepass_kernel<<<2048, block, 0, stream>>>((const float4*)emb, oscale,
                                                     h2, n_total, n_nodes);
        sortagg_kernel<<<nb, 512, 0, stream>>>(h2, arrA, dbstart, out, n_nodes);
    } else {
        int* foutdeg = (int*)d_ws;
        int* findeg = foutdeg + n_nodes;
        long long n_out = (long long)n_nodes * D_FEAT;
        fb_zero<<<2048, block, 0, stream>>>(out, n_out, foutdeg, 2 * n_nodes);
        fb_degree<<<2048, block, 0, stream>>>(src, dst, n_edges, foutdeg, findeg);
        fb_scatter<<<2048, block, 0, stream>>>(emb, src, dst, foutdeg, out, n_edges);
        fb_scale<<<2048, block, 0, stream>>>(out, findeg, n_out);
    }
}